// Round 2
// baseline (506.639 us; speedup 1.0000x reference)
//
#include <hip/hip_runtime.h>

#define H 1024
#define S 2048
#define B 32
#define M (S*B)

typedef short bf16x8 __attribute__((ext_vector_type(8)));
typedef float f32x4 __attribute__((ext_vector_type(4)));

__device__ __forceinline__ unsigned short f2bf(float f) {
    unsigned int u = __builtin_bit_cast(unsigned int, f);
    u += 0x7FFFu + ((u >> 16) & 1u);
    return (unsigned short)(u >> 16);
}

// ---------------- We -> We^T (bf16) ----------------
__global__ __launch_bounds__(256) void transpose_we(const float* __restrict__ We,
                                                    unsigned short* __restrict__ WeT) {
    __shared__ float t[64][65];
    int tx = threadIdx.x & 63, ty = threadIdx.x >> 6;
    int n0 = blockIdx.x * 64, k0 = blockIdx.y * 64;
#pragma unroll
    for (int q = 0; q < 16; ++q) {
        int kk = ty * 16 + q;
        t[kk][tx] = We[(size_t)(k0 + kk) * H + n0 + tx];
    }
    __syncthreads();
#pragma unroll
    for (int q = 0; q < 16; ++q) {
        int nn = ty * 16 + q;
        WeT[(size_t)(n0 + nn) * H + k0 + tx] = f2bf(t[tx][nn]);
    }
}

// ---------------- d[b][j] = dec[b] @ Wd ----------------
__global__ __launch_bounds__(256) void dec_proj(const float* __restrict__ dec,
                                                const float* __restrict__ Wd,
                                                float* __restrict__ dvec) {
    __shared__ float ds[H];
    int b = blockIdx.y, jc = blockIdx.x, t = threadIdx.x;
    for (int i = t; i < H; i += 256) ds[i] = dec[b * H + i];
    __syncthreads();
    int j = jc * 256 + t;
    float acc = 0.f;
#pragma unroll 8
    for (int h = 0; h < H; ++h) acc += ds[h] * Wd[(size_t)h * H + j];
    dvec[b * H + j] = acc;
}

// ---------------- fused GEMM: part[rg][bn] = sum_j v[j]*tanh(d[b][j] + enc[rg]@We[:,j]) ----------------
__global__ __launch_bounds__(256) void gemm_logits(const float* __restrict__ enc,
                                                   const unsigned short* __restrict__ WeT,
                                                   const float* __restrict__ dvec,
                                                   const float* __restrict__ v,
                                                   float* __restrict__ part) {
    __shared__ unsigned short As[128 * 64];
    __shared__ unsigned short Bs[128 * 64];
    int tid = threadIdx.x;
    int bid = blockIdx.x;
    // XCD-chunked swizzle: 4096 blocks, XCD x gets a contiguous m-range, all 8 n-blocks adjacent
    int swz = (bid & 7) * 512 + (bid >> 3);
    int bm = swz >> 3, bn = swz & 7;
    int lane = tid & 63, wid = tid >> 6;
    int wm = wid >> 1, wn = wid & 1;

    f32x4 acc[4][4] = {};

    int r = tid >> 1, halfk = tid & 1;
    const float* asrc = enc + ((size_t)(bm * 128 + r)) * H + halfk * 32;
    const unsigned short* bsrc = WeT + ((size_t)(bn * 128 + r)) * H + halfk * 32;
    int wbase = r * 64;          // ushort index of row r in LDS tile
    int rmask = r & 7;

    for (int kt = 0; kt < 16; ++kt) {
        if (kt) __syncthreads();
        // stage A (f32 -> bf16, swizzled)
        {
            const float4* s4 = (const float4*)(asrc + kt * 64);
            float4 f[8];
#pragma unroll
            for (int q = 0; q < 8; ++q) f[q] = s4[q];
#pragma unroll
            for (int j = 0; j < 4; ++j) {
                float4 x = f[2 * j], y = f[2 * j + 1];
                bf16x8 c;
                c[0] = (short)f2bf(x.x); c[1] = (short)f2bf(x.y);
                c[2] = (short)f2bf(x.z); c[3] = (short)f2bf(x.w);
                c[4] = (short)f2bf(y.x); c[5] = (short)f2bf(y.y);
                c[6] = (short)f2bf(y.z); c[7] = (short)f2bf(y.w);
                *(bf16x8*)&As[wbase + (((halfk * 4 + j) ^ rmask) * 8)] = c;
            }
        }
        // stage B (already bf16, swizzled)
        {
            const bf16x8* s8 = (const bf16x8*)(bsrc + kt * 64);
#pragma unroll
            for (int j = 0; j < 4; ++j) {
                bf16x8 val = s8[j];
                *(bf16x8*)&Bs[wbase + (((halfk * 4 + j) ^ rmask) * 8)] = val;
            }
        }
        __syncthreads();
#pragma unroll
        for (int kh = 0; kh < 2; ++kh) {
            bf16x8 a[4], bfr[4];
#pragma unroll
            for (int m = 0; m < 4; ++m) {
                int row = wm * 64 + m * 16 + (lane & 15);
                int slot = (kh * 4 + (lane >> 4)) ^ (row & 7);
                a[m] = *(const bf16x8*)&As[row * 64 + slot * 8];
            }
#pragma unroll
            for (int n = 0; n < 4; ++n) {
                int row = wn * 64 + n * 16 + (lane & 15);
                int slot = (kh * 4 + (lane >> 4)) ^ (row & 7);
                bfr[n] = *(const bf16x8*)&Bs[row * 64 + slot * 8];
            }
#pragma unroll
            for (int m = 0; m < 4; ++m)
#pragma unroll
                for (int n = 0; n < 4; ++n)
                    acc[m][n] = __builtin_amdgcn_mfma_f32_16x16x32_bf16(a[m], bfr[n], acc[m][n], 0, 0, 0);
        }
    }

    // epilogue: partial logit over this wave's 64 j's = sum_j v[j]*tanh(d[b][j] + e)
    float vj[4];
#pragma unroll
    for (int n = 0; n < 4; ++n) vj[n] = v[bn * 128 + wn * 64 + n * 16 + (lane & 15)];
    float pv[4][4];
#pragma unroll
    for (int m = 0; m < 4; ++m) {
#pragma unroll
        for (int i = 0; i < 4; ++i) {
            int rg = bm * 128 + wm * 64 + m * 16 + (lane >> 4) * 4 + i;
            int bb = rg & (B - 1);   // row = s*B + b
            float p = 0.f;
#pragma unroll
            for (int n = 0; n < 4; ++n) {
                int j = bn * 128 + wn * 64 + n * 16 + (lane & 15);
                p += vj[n] * tanhf(dvec[bb * H + j] + acc[m][n][i]);
            }
            // butterfly: all 16 lanes of the group end up with the group sum
            p += __shfl_xor(p, 1);
            p += __shfl_xor(p, 2);
            p += __shfl_xor(p, 4);
            p += __shfl_xor(p, 8);
            pv[m][i] = p;
        }
    }
    // combine the two wn-halves of each row via LDS (was a write race before)
    __syncthreads();                 // done reading As/Bs
    float* red = (float*)As;         // 128 floats scratch
    if (wn == 1) {
#pragma unroll
        for (int m = 0; m < 4; ++m)
#pragma unroll
            for (int i = 0; i < 4; ++i) {
                int rl = wm * 64 + m * 16 + (lane >> 4) * 4 + i;
                if ((lane & 15) == 0) red[rl] = pv[m][i];
            }
    }
    __syncthreads();
    if (wn == 0) {
#pragma unroll
        for (int m = 0; m < 4; ++m)
#pragma unroll
            for (int i = 0; i < 4; ++i) {
                int rl = wm * 64 + m * 16 + (lane >> 4) * 4 + i;
                int rg = bm * 128 + rl;
                if ((lane & 15) == 0) part[(size_t)rg * 8 + bn] = pv[m][i] + red[rl];
            }
    }
}

// ---------------- softmax over s per b ----------------
__global__ __launch_bounds__(256) void softmax_k(const float* __restrict__ part,
                                                 float* __restrict__ scores) {
    int b = blockIdx.x, tid = threadIdx.x;
    int lane = tid & 63, wid = tid >> 6;
    __shared__ float red[4];
    __shared__ float red2[4];
    float lg[8];
    float mx = -1e30f;
#pragma unroll
    for (int q = 0; q < 8; ++q) {
        int s = q * 256 + tid;
        const float4* pr = (const float4*)(part + ((size_t)(s * B + b)) * 8);
        float4 x = pr[0], y = pr[1];
        float L = ((x.x + x.y) + (x.z + x.w)) + ((y.x + y.y) + (y.z + y.w));
        lg[q] = L;
        mx = fmaxf(mx, L);
    }
#pragma unroll
    for (int off = 32; off; off >>= 1) mx = fmaxf(mx, __shfl_xor(mx, off));
    if (lane == 0) red[wid] = mx;
    __syncthreads();
    mx = fmaxf(fmaxf(red[0], red[1]), fmaxf(red[2], red[3]));
    float sum = 0.f;
#pragma unroll
    for (int q = 0; q < 8; ++q) {
        lg[q] = expf(lg[q] - mx);
        sum += lg[q];
    }
#pragma unroll
    for (int off = 32; off; off >>= 1) sum += __shfl_xor(sum, off);
    if (lane == 0) red2[wid] = sum;
    __syncthreads();
    sum = (red2[0] + red2[1]) + (red2[2] + red2[3]);
    float inv = 1.f / sum;
#pragma unroll
    for (int q = 0; q < 8; ++q) scores[b * S + q * 256 + tid] = lg[q] * inv;
}

// ---------------- attn_values partials: sum over an S-chunk ----------------
__global__ __launch_bounds__(256) void weighted_sum(const float* __restrict__ enc,
                                                    const float* __restrict__ scores,
                                                    float* __restrict__ part2) {
    __shared__ float sl[512];
    int t = threadIdx.x;
    int hx = blockIdx.x, b = blockIdx.y, sc = blockIdx.z;
    sl[t] = scores[b * S + sc * 512 + t];
    sl[t + 256] = scores[b * S + sc * 512 + t + 256];
    __syncthreads();
    int h = hx * 256 + t;
    const float* ep = enc + ((size_t)(sc * 512) * B) * H + (size_t)b * H + h;
    float acc = 0.f;
#pragma unroll 4
    for (int s = 0; s < 512; ++s) acc += ep[(size_t)s * B * H] * sl[s];
    part2[((size_t)sc * B + b) * H + h] = acc;
}

__global__ __launch_bounds__(256) void reduce_vals(const float* __restrict__ part2,
                                                   float* __restrict__ out) {
    int i = blockIdx.x * 256 + threadIdx.x;
    out[i] = (part2[i] + part2[B * H + i]) + (part2[2 * B * H + i] + part2[3 * B * H + i]);
}

extern "C" void kernel_launch(void* const* d_in, const int* in_sizes, int n_in,
                              void* d_out, int out_size, void* d_ws, size_t ws_size,
                              hipStream_t stream) {
    const float* dec = (const float*)d_in[0];   // [1,B,H]
    const float* enc = (const float*)d_in[1];   // [S,B,H]
    const float* Wd  = (const float*)d_in[2];   // [H,H]
    const float* We  = (const float*)d_in[3];   // [H,H]
    const float* v   = (const float*)d_in[4];   // [H]
    float* out = (float*)d_out;                 // [B*H] values, then [B*S] scores

    char* ws = (char*)d_ws;
    unsigned short* WeT = (unsigned short*)ws;                          // 2 MB
    float* dvec  = (float*)(ws + (2u << 20));                           // 128 KB
    float* part  = (float*)(ws + (2u << 20) + (1u << 18));              // 2 MB
    float* part2 = (float*)(ws + (4u << 20) + (1u << 18));              // 512 KB

    transpose_we<<<dim3(16, 16), 256, 0, stream>>>(We, WeT);
    dec_proj<<<dim3(4, B), 256, 0, stream>>>(dec, Wd, dvec);
    gemm_logits<<<4096, 256, 0, stream>>>(enc, WeT, dvec, v, part);
    softmax_k<<<B, 256, 0, stream>>>(part, out + B * H);
    weighted_sum<<<dim3(4, B, 4), 256, 0, stream>>>(enc, out + B * H, part2);
    reduce_vals<<<128, 256, 0, stream>>>(part2, out);
}

// Round 3
// 421.282 us; speedup vs baseline: 1.2026x; 1.2026x over previous
//
#include <hip/hip_runtime.h>

#define H 1024
#define S 2048
#define B 32
#define M (S*B)

typedef short bf16x8 __attribute__((ext_vector_type(8)));
typedef float f32x4 __attribute__((ext_vector_type(4)));

__device__ __forceinline__ unsigned short f2bf(float f) {
    unsigned int u = __builtin_bit_cast(unsigned int, f);
    u += 0x7FFFu + ((u >> 16) & 1u);
    return (unsigned short)(u >> 16);
}

__device__ __forceinline__ void gload_lds16(const void* g, void* l) {
    __builtin_amdgcn_global_load_lds((const __attribute__((address_space(1))) void*)g,
                                     (__attribute__((address_space(3))) void*)l, 16, 0, 0);
}

// ---------------- enc f32 -> bf16 ----------------
__global__ __launch_bounds__(256) void convert_enc(const float* __restrict__ enc,
                                                   unsigned short* __restrict__ encBF) {
    const size_t total = (size_t)M * H / 8;
    for (size_t idx = (size_t)blockIdx.x * 256 + threadIdx.x; idx < total;
         idx += (size_t)gridDim.x * 256) {
        const float4* p = (const float4*)(enc + idx * 8);
        float4 x = p[0], y = p[1];
        bf16x8 c;
        c[0] = (short)f2bf(x.x); c[1] = (short)f2bf(x.y);
        c[2] = (short)f2bf(x.z); c[3] = (short)f2bf(x.w);
        c[4] = (short)f2bf(y.x); c[5] = (short)f2bf(y.y);
        c[6] = (short)f2bf(y.z); c[7] = (short)f2bf(y.w);
        *(bf16x8*)(encBF + idx * 8) = c;
    }
}

// ---------------- We -> We^T (bf16) ----------------
__global__ __launch_bounds__(256) void transpose_we(const float* __restrict__ We,
                                                    unsigned short* __restrict__ WeT) {
    __shared__ float t[64][65];
    int tx = threadIdx.x & 63, ty = threadIdx.x >> 6;
    int n0 = blockIdx.x * 64, k0 = blockIdx.y * 64;
#pragma unroll
    for (int q = 0; q < 16; ++q) {
        int kk = ty * 16 + q;
        t[kk][tx] = We[(size_t)(k0 + kk) * H + n0 + tx];
    }
    __syncthreads();
#pragma unroll
    for (int q = 0; q < 16; ++q) {
        int nn = ty * 16 + q;
        WeT[(size_t)(n0 + nn) * H + k0 + tx] = f2bf(t[tx][nn]);
    }
}

// ---------------- d[b][j] = dec[b] @ Wd ----------------
__global__ __launch_bounds__(256) void dec_proj(const float* __restrict__ dec,
                                                const float* __restrict__ Wd,
                                                float* __restrict__ dvec) {
    __shared__ float ds[H];
    int b = blockIdx.y, jc = blockIdx.x, t = threadIdx.x;
    for (int i = t; i < H; i += 256) ds[i] = dec[b * H + i];
    __syncthreads();
    int j = jc * 256 + t;
    float acc = 0.f;
#pragma unroll 8
    for (int h = 0; h < H; ++h) acc += ds[h] * Wd[(size_t)h * H + j];
    dvec[b * H + j] = acc;
}

// ---------------- m97-structure fused GEMM (bf16 A and B, global_load_lds) ----------------
// LDS linear (row, slot) holds global (row, slot ^ (row&7)); ds_read applies the same XOR.
__global__ __launch_bounds__(256) void gemm_logits2(const unsigned short* __restrict__ encBF,
                                                    const unsigned short* __restrict__ WeT,
                                                    const float* __restrict__ dvec,
                                                    const float* __restrict__ v,
                                                    float* __restrict__ part) {
    __shared__ unsigned short As[128 * 64];
    __shared__ unsigned short Bs[128 * 64];
    int tid = threadIdx.x, bid = blockIdx.x;
    int swz = (bid & 7) * 512 + (bid >> 3);
    int bm = swz >> 3, bn = swz & 7;
    int lane = tid & 63, wid = tid >> 6;
    int wm = wid >> 1, wn = wid & 1;

    f32x4 acc[4][4] = {};

    // chunk c = wid*4+q covers tile rows [c*8, c*8+8); lane l -> row c*8+(l>>3), LDS slot l&7.
    // source slot pre-swizzled so LDS stays linear for global_load_lds.
    int rsub = lane >> 3;
    int gslot = (lane & 7) ^ rsub;   // (row&7) == rsub since c*8 is 8-aligned
    const unsigned short* aP[4];
    const unsigned short* bP[4];
    unsigned short* aL[4];
    unsigned short* bL[4];
#pragma unroll
    for (int q = 0; q < 4; ++q) {
        int c = wid * 4 + q;
        int grow = c * 8 + rsub;
        aP[q] = encBF + (size_t)(bm * 128 + grow) * H + gslot * 8;
        bP[q] = WeT + (size_t)(bn * 128 + grow) * H + gslot * 8;
        aL[q] = &As[c * 512];
        bL[q] = &Bs[c * 512];
    }

    for (int kt = 0; kt < 16; ++kt) {
        if (kt) __syncthreads();
#pragma unroll
        for (int q = 0; q < 4; ++q) gload_lds16(aP[q] + kt * 64, aL[q]);
#pragma unroll
        for (int q = 0; q < 4; ++q) gload_lds16(bP[q] + kt * 64, bL[q]);
        __syncthreads();
#pragma unroll
        for (int kh = 0; kh < 2; ++kh) {
            bf16x8 a[4], bfr[4];
#pragma unroll
            for (int m = 0; m < 4; ++m) {
                int row = wm * 64 + m * 16 + (lane & 15);
                int slot = (kh * 4 + (lane >> 4)) ^ (row & 7);
                a[m] = *(const bf16x8*)&As[row * 64 + slot * 8];
            }
#pragma unroll
            for (int n = 0; n < 4; ++n) {
                int row = wn * 64 + n * 16 + (lane & 15);
                int slot = (kh * 4 + (lane >> 4)) ^ (row & 7);
                bfr[n] = *(const bf16x8*)&Bs[row * 64 + slot * 8];
            }
#pragma unroll
            for (int m = 0; m < 4; ++m)
#pragma unroll
                for (int n = 0; n < 4; ++n)
                    acc[m][n] = __builtin_amdgcn_mfma_f32_16x16x32_bf16(a[m], bfr[n], acc[m][n], 0, 0, 0);
        }
    }

    // epilogue: partial logit over this wave's 64 j's = sum_j v[j]*tanh(d[b][j] + e)
    float vj[4];
#pragma unroll
    for (int n = 0; n < 4; ++n) vj[n] = v[bn * 128 + wn * 64 + n * 16 + (lane & 15)];
    float pv[4][4];
#pragma unroll
    for (int m = 0; m < 4; ++m) {
#pragma unroll
        for (int i = 0; i < 4; ++i) {
            int rg = bm * 128 + wm * 64 + m * 16 + (lane >> 4) * 4 + i;
            int bb = rg & (B - 1);   // row = s*B + b
            float p = 0.f;
#pragma unroll
            for (int n = 0; n < 4; ++n) {
                int j = bn * 128 + wn * 64 + n * 16 + (lane & 15);
                p += vj[n] * tanhf(dvec[bb * H + j] + acc[m][n][i]);
            }
            p += __shfl_xor(p, 1);
            p += __shfl_xor(p, 2);
            p += __shfl_xor(p, 4);
            p += __shfl_xor(p, 8);
            pv[m][i] = p;
        }
    }
    __syncthreads();
    float* red = (float*)As;
    if (wn == 1) {
#pragma unroll
        for (int m = 0; m < 4; ++m)
#pragma unroll
            for (int i = 0; i < 4; ++i) {
                int rl = wm * 64 + m * 16 + (lane >> 4) * 4 + i;
                if ((lane & 15) == 0) red[rl] = pv[m][i];
            }
    }
    __syncthreads();
    if (wn == 0) {
#pragma unroll
        for (int m = 0; m < 4; ++m)
#pragma unroll
            for (int i = 0; i < 4; ++i) {
                int rl = wm * 64 + m * 16 + (lane >> 4) * 4 + i;
                int rg = bm * 128 + rl;
                if ((lane & 15) == 0) part[(size_t)rg * 8 + bn] = pv[m][i] + red[rl];
            }
    }
}

// ---------------- fallback GEMM (R2, reg-staged from f32 enc) ----------------
__global__ __launch_bounds__(256) void gemm_logits(const float* __restrict__ enc,
                                                   const unsigned short* __restrict__ WeT,
                                                   const float* __restrict__ dvec,
                                                   const float* __restrict__ v,
                                                   float* __restrict__ part) {
    __shared__ unsigned short As[128 * 64];
    __shared__ unsigned short Bs[128 * 64];
    int tid = threadIdx.x, bid = blockIdx.x;
    int swz = (bid & 7) * 512 + (bid >> 3);
    int bm = swz >> 3, bn = swz & 7;
    int lane = tid & 63, wid = tid >> 6;
    int wm = wid >> 1, wn = wid & 1;
    f32x4 acc[4][4] = {};
    int r = tid >> 1, halfk = tid & 1;
    const float* asrc = enc + ((size_t)(bm * 128 + r)) * H + halfk * 32;
    const unsigned short* bsrc = WeT + ((size_t)(bn * 128 + r)) * H + halfk * 32;
    int wbase = r * 64;
    int rmask = r & 7;
    for (int kt = 0; kt < 16; ++kt) {
        if (kt) __syncthreads();
        {
            const float4* s4 = (const float4*)(asrc + kt * 64);
            float4 f[8];
#pragma unroll
            for (int q = 0; q < 8; ++q) f[q] = s4[q];
#pragma unroll
            for (int j = 0; j < 4; ++j) {
                float4 x = f[2 * j], y = f[2 * j + 1];
                bf16x8 c;
                c[0] = (short)f2bf(x.x); c[1] = (short)f2bf(x.y);
                c[2] = (short)f2bf(x.z); c[3] = (short)f2bf(x.w);
                c[4] = (short)f2bf(y.x); c[5] = (short)f2bf(y.y);
                c[6] = (short)f2bf(y.z); c[7] = (short)f2bf(y.w);
                *(bf16x8*)&As[wbase + (((halfk * 4 + j) ^ rmask) * 8)] = c;
            }
        }
        {
            const bf16x8* s8 = (const bf16x8*)(bsrc + kt * 64);
#pragma unroll
            for (int j = 0; j < 4; ++j) {
                bf16x8 val = s8[j];
                *(bf16x8*)&Bs[wbase + (((halfk * 4 + j) ^ rmask) * 8)] = val;
            }
        }
        __syncthreads();
#pragma unroll
        for (int kh = 0; kh < 2; ++kh) {
            bf16x8 a[4], bfr[4];
#pragma unroll
            for (int m = 0; m < 4; ++m) {
                int row = wm * 64 + m * 16 + (lane & 15);
                int slot = (kh * 4 + (lane >> 4)) ^ (row & 7);
                a[m] = *(const bf16x8*)&As[row * 64 + slot * 8];
            }
#pragma unroll
            for (int n = 0; n < 4; ++n) {
                int row = wn * 64 + n * 16 + (lane & 15);
                int slot = (kh * 4 + (lane >> 4)) ^ (row & 7);
                bfr[n] = *(const bf16x8*)&Bs[row * 64 + slot * 8];
            }
#pragma unroll
            for (int m = 0; m < 4; ++m)
#pragma unroll
                for (int n = 0; n < 4; ++n)
                    acc[m][n] = __builtin_amdgcn_mfma_f32_16x16x32_bf16(a[m], bfr[n], acc[m][n], 0, 0, 0);
        }
    }
    float vj[4];
#pragma unroll
    for (int n = 0; n < 4; ++n) vj[n] = v[bn * 128 + wn * 64 + n * 16 + (lane & 15)];
    float pv[4][4];
#pragma unroll
    for (int m = 0; m < 4; ++m) {
#pragma unroll
        for (int i = 0; i < 4; ++i) {
            int rg = bm * 128 + wm * 64 + m * 16 + (lane >> 4) * 4 + i;
            int bb = rg & (B - 1);
            float p = 0.f;
#pragma unroll
            for (int n = 0; n < 4; ++n) {
                int j = bn * 128 + wn * 64 + n * 16 + (lane & 15);
                p += vj[n] * tanhf(dvec[bb * H + j] + acc[m][n][i]);
            }
            p += __shfl_xor(p, 1);
            p += __shfl_xor(p, 2);
            p += __shfl_xor(p, 4);
            p += __shfl_xor(p, 8);
            pv[m][i] = p;
        }
    }
    __syncthreads();
    float* red = (float*)As;
    if (wn == 1) {
#pragma unroll
        for (int m = 0; m < 4; ++m)
#pragma unroll
            for (int i = 0; i < 4; ++i) {
                int rl = wm * 64 + m * 16 + (lane >> 4) * 4 + i;
                if ((lane & 15) == 0) red[rl] = pv[m][i];
            }
    }
    __syncthreads();
    if (wn == 0) {
#pragma unroll
        for (int m = 0; m < 4; ++m)
#pragma unroll
            for (int i = 0; i < 4; ++i) {
                int rl = wm * 64 + m * 16 + (lane >> 4) * 4 + i;
                int rg = bm * 128 + rl;
                if ((lane & 15) == 0) part[(size_t)rg * 8 + bn] = pv[m][i] + red[rl];
            }
    }
}

// ---------------- softmax over s per b ----------------
__global__ __launch_bounds__(256) void softmax_k(const float* __restrict__ part,
                                                 float* __restrict__ scores) {
    int b = blockIdx.x, tid = threadIdx.x;
    int lane = tid & 63, wid = tid >> 6;
    __shared__ float red[4];
    __shared__ float red2[4];
    float lg[8];
    float mx = -1e30f;
#pragma unroll
    for (int q = 0; q < 8; ++q) {
        int s = q * 256 + tid;
        const float4* pr = (const float4*)(part + ((size_t)(s * B + b)) * 8);
        float4 x = pr[0], y = pr[1];
        float L = ((x.x + x.y) + (x.z + x.w)) + ((y.x + y.y) + (y.z + y.w));
        lg[q] = L;
        mx = fmaxf(mx, L);
    }
#pragma unroll
    for (int off = 32; off; off >>= 1) mx = fmaxf(mx, __shfl_xor(mx, off));
    if (lane == 0) red[wid] = mx;
    __syncthreads();
    mx = fmaxf(fmaxf(red[0], red[1]), fmaxf(red[2], red[3]));
    float sum = 0.f;
#pragma unroll
    for (int q = 0; q < 8; ++q) {
        lg[q] = expf(lg[q] - mx);
        sum += lg[q];
    }
#pragma unroll
    for (int off = 32; off; off >>= 1) sum += __shfl_xor(sum, off);
    if (lane == 0) red2[wid] = sum;
    __syncthreads();
    sum = (red2[0] + red2[1]) + (red2[2] + red2[3]);
    float inv = 1.f / sum;
#pragma unroll
    for (int q = 0; q < 8; ++q) scores[b * S + q * 256 + tid] = lg[q] * inv;
}

// ---------------- attn_values partials: sum over an S-chunk ----------------
__global__ __launch_bounds__(256) void weighted_sum(const float* __restrict__ enc,
                                                    const float* __restrict__ scores,
                                                    float* __restrict__ part2) {
    __shared__ float sl[512];
    int t = threadIdx.x;
    int hx = blockIdx.x, b = blockIdx.y, sc = blockIdx.z;
    sl[t] = scores[b * S + sc * 512 + t];
    sl[t + 256] = scores[b * S + sc * 512 + t + 256];
    __syncthreads();
    int h = hx * 256 + t;
    const float* ep = enc + ((size_t)(sc * 512) * B) * H + (size_t)b * H + h;
    float acc = 0.f;
#pragma unroll 4
    for (int s = 0; s < 512; ++s) acc += ep[(size_t)s * B * H] * sl[s];
    part2[((size_t)sc * B + b) * H + h] = acc;
}

__global__ __launch_bounds__(256) void reduce_vals(const float* __restrict__ part2,
                                                   float* __restrict__ out) {
    int i = blockIdx.x * 256 + threadIdx.x;
    out[i] = (part2[i] + part2[B * H + i]) + (part2[2 * B * H + i] + part2[3 * B * H + i]);
}

extern "C" void kernel_launch(void* const* d_in, const int* in_sizes, int n_in,
                              void* d_out, int out_size, void* d_ws, size_t ws_size,
                              hipStream_t stream) {
    const float* dec = (const float*)d_in[0];   // [1,B,H]
    const float* enc = (const float*)d_in[1];   // [S,B,H]
    const float* Wd  = (const float*)d_in[2];   // [H,H]
    const float* We  = (const float*)d_in[3];   // [H,H]
    const float* v   = (const float*)d_in[4];   // [H]
    float* out = (float*)d_out;                 // [B*H] values, then [B*S] scores

    char* ws = (char*)d_ws;
    unsigned short* WeT = (unsigned short*)ws;                          // 2 MB
    float* dvec  = (float*)(ws + (2u << 20));                           // 128 KB
    float* part  = (float*)(ws + (2u << 20) + (1u << 18));              // 2 MB
    float* part2 = (float*)(ws + (4u << 20) + (1u << 18));              // 512 KB
    size_t encBFoff = (size_t)8 << 20;
    size_t need = encBFoff + (size_t)M * H * 2;                         // 8 MB + 128 MB

    transpose_we<<<dim3(16, 16), 256, 0, stream>>>(We, WeT);
    dec_proj<<<dim3(4, B), 256, 0, stream>>>(dec, Wd, dvec);
    if (ws_size >= need) {
        unsigned short* encBF = (unsigned short*)(ws + encBFoff);
        convert_enc<<<2048, 256, 0, stream>>>(enc, encBF);
        gemm_logits2<<<4096, 256, 0, stream>>>(encBF, WeT, dvec, v, part);
    } else {
        gemm_logits<<<4096, 256, 0, stream>>>(enc, WeT, dvec, v, part);
    }
    softmax_k<<<B, 256, 0, stream>>>(part, out + B * H);
    weighted_sum<<<dim3(4, B, 4), 256, 0, stream>>>(enc, out + B * H, part2);
    reduce_vals<<<128, 256, 0, stream>>>(part2, out);
}